// Round 4
// baseline (2072.573 us; speedup 1.0000x reference)
//
#include <hip/hip_runtime.h>
#include <hip/hip_bf16.h>
#include <cstdint>
#include <cstddef>

typedef __bf16 bf16_t;
typedef __bf16 bf16x8 __attribute__((ext_vector_type(8)));
typedef float  f32x4  __attribute__((ext_vector_type(4)));

#define MFMA16(a, b, c) __builtin_amdgcn_mfma_f32_16x16x32_bf16((a), (b), (c), 0, 0, 0)

__device__ __forceinline__ void gload_lds16(const void* g, void* l) {
  __builtin_amdgcn_global_load_lds(
      (__attribute__((address_space(1))) void*)(g),
      (__attribute__((address_space(3))) void*)(l), 16, 0, 0);
}

// ---------------- elementwise f32 -> bf16 (vectorized) ----------------
__global__ void k_f32_to_bf16(const float* __restrict__ in, bf16_t* __restrict__ out, size_t n4) {
  size_t i = (size_t)blockIdx.x * blockDim.x + threadIdx.x;
  size_t stride = (size_t)gridDim.x * blockDim.x;
  for (; i < n4; i += stride) {
    float4 v = ((const float4*)in)[i];
    union { bf16_t b[4]; ushort4 u; } pk;
    pk.b[0] = (bf16_t)v.x; pk.b[1] = (bf16_t)v.y;
    pk.b[2] = (bf16_t)v.z; pk.b[3] = (bf16_t)v.w;
    ((ushort4*)out)[i] = pk.u;
  }
}

// ---------------- tiled transpose f32 (R,C) -> bf16 (Cpad,R); pad rows zeroed ----
__global__ void k_transpose_f32_bf16(const float* __restrict__ in, bf16_t* __restrict__ out,
                                     int R, int C, int ldin, int ldout) {
  __shared__ float t[32][33];
  int r0 = blockIdx.x * 32, c0 = blockIdx.y * 32;
  int tx = threadIdx.x, ty = threadIdx.y;
#pragma unroll
  for (int i = 0; i < 4; ++i) {
    int c = c0 + tx;
    float v = (c < C) ? in[(size_t)(r0 + ty + i * 8) * ldin + c] : 0.0f;
    t[ty + i * 8][tx] = v;
  }
  __syncthreads();
#pragma unroll
  for (int i = 0; i < 4; ++i) {
    int oc = c0 + ty + i * 8;
    out[(size_t)oc * ldout + r0 + tx] = (bf16_t)t[tx][ty + i * 8];
  }
}

// ---------------- rope cos/sin tables (position_ids arrive as int32!) ----------------
__global__ void k_build_rope(const int* __restrict__ pos,
                             float* __restrict__ cosT, float* __restrict__ sinT) {
  int s = blockIdx.x, j = threadIdx.x;  // 64 threads
  int i = j & 31;
  float invf = __expf(-((float)i / 32.0f) * 9.210340371976184f);  // ln(10000)
  float ang = (float)pos[s] * invf;
  cosT[s * 64 + j] = cosf(ang);
  sinT[s * 64 + j] = sinf(ang);
}

// ---------------- GEMM: C(M,N) = A(M,K) * Bt(N,K)^T, bf16 in, f32 acc ----------------
template <int BM, int BN, int WM, int WN, int OUTF32>
__global__ __launch_bounds__(256) void k_gemm_tn(
    const bf16_t* __restrict__ A, const bf16_t* __restrict__ Bt,
    float* __restrict__ Cf, bf16_t* __restrict__ Cb,
    int Nreal, int K, int lda, int ldb, int ldc) {
  constexpr int MI = BM / WM / 16;
  constexpr int NI = BN / WN / 16;
  __shared__ __align__(16) bf16_t As[BM * 32];
  __shared__ __align__(16) bf16_t Bs[BN * 32];
  const int tid = threadIdx.x, lane = tid & 63, w = tid >> 6;
  const int wm = w / WN, wn = w % WN;
  const int row0 = blockIdx.y * BM, col0 = blockIdx.x * BN;
  const int lr = lane & 15, lg = lane >> 4;
  const int srow = lane >> 2;          // staging: row within 16-row chunk
  const int scol = (lane & 3) * 8;     // staging: element col
  f32x4 acc[MI][NI];
#pragma unroll
  for (int mi = 0; mi < MI; ++mi)
#pragma unroll
    for (int ni = 0; ni < NI; ++ni)
      acc[mi][ni] = (f32x4){0.f, 0.f, 0.f, 0.f};

  for (int k0 = 0; k0 < K; k0 += 32) {
    __syncthreads();
#pragma unroll
    for (int i = 0; i < BM / 64; ++i) {
      int chunk = w * (BM / 64) + i;
      gload_lds16(A + (size_t)(row0 + chunk * 16 + srow) * lda + k0 + scol, &As[chunk * 512]);
    }
#pragma unroll
    for (int i = 0; i < BN / 64; ++i) {
      int chunk = w * (BN / 64) + i;
      gload_lds16(Bt + (size_t)(col0 + chunk * 16 + srow) * ldb + k0 + scol, &Bs[chunk * 512]);
    }
    __syncthreads();
    bf16x8 af[MI], bfv[NI];
#pragma unroll
    for (int mi = 0; mi < MI; ++mi)
      af[mi] = *(const bf16x8*)&As[(wm * MI * 16 + mi * 16 + lr) * 32 + lg * 8];
#pragma unroll
    for (int ni = 0; ni < NI; ++ni)
      bfv[ni] = *(const bf16x8*)&Bs[(wn * NI * 16 + ni * 16 + lr) * 32 + lg * 8];
#pragma unroll
    for (int mi = 0; mi < MI; ++mi)
#pragma unroll
      for (int ni = 0; ni < NI; ++ni)
        acc[mi][ni] = MFMA16(af[mi], bfv[ni], acc[mi][ni]);
  }
#pragma unroll
  for (int mi = 0; mi < MI; ++mi)
#pragma unroll
    for (int ni = 0; ni < NI; ++ni)
#pragma unroll
      for (int r = 0; r < 4; ++r) {
        int row = row0 + wm * MI * 16 + mi * 16 + lg * 4 + r;
        int col = col0 + wn * NI * 16 + ni * 16 + lr;
        if (col < Nreal) {
          if (OUTF32) Cf[(size_t)row * ldc + col] = acc[mi][ni][r];
          else        Cb[(size_t)row * ldc + col] = (bf16_t)acc[mi][ni][r];
        }
      }
}

// ---------------- rmsnorm (f32 in, bf16 out) ----------------
template <int D>
__global__ __launch_bounds__(256) void k_rmsnorm(const float* __restrict__ in,
                                                 const float* __restrict__ wgt,
                                                 bf16_t* __restrict__ out, int ldin, int ldout) {
  int row = blockIdx.x;
  const float* x = in + (size_t)row * ldin;
  float ss = 0.f;
#pragma unroll
  for (int i = threadIdx.x; i < D; i += 256) { float v = x[i]; ss += v * v; }
#pragma unroll
  for (int off = 32; off > 0; off >>= 1) ss += __shfl_down(ss, off);
  __shared__ float red[4];
  if ((threadIdx.x & 63) == 0) red[threadIdx.x >> 6] = ss;
  __syncthreads();
  float tot = red[0] + red[1] + red[2] + red[3];
  float rs = rsqrtf(tot / (float)D + 1e-6f);
#pragma unroll
  for (int i = threadIdx.x; i < D; i += 256)
    out[(size_t)row * ldout + i] = (bf16_t)(x[i] * rs * wgt[i]);
}

// ---------------- rope on q_pe (in-place on Q buffer, bf16) ----------------
__global__ void k_rope_q(bf16_t* __restrict__ Q, const float* __restrict__ cosT,
                         const float* __restrict__ sinT) {
  int idx = blockIdx.x * blockDim.x + threadIdx.x;  // s*128*32 total
  int d = idx & 31, h = (idx >> 5) & 127, s = idx >> 12;
  bf16_t* qp = Q + (size_t)s * 24576 + h * 192 + 128;
  float c = cosT[s * 64 + d], sn = sinT[s * 64 + d];
  float x1 = (float)qp[d], x2 = (float)qp[d + 32];
  qp[d]      = (bf16_t)(x1 * c - x2 * sn);
  qp[d + 32] = (bf16_t)(x2 * c + x1 * sn);
}

// ---------------- rope on k_pe (f32 kv_a cols 512.. -> bf16 kpe) ----------------
__global__ void k_rope_k(const float* __restrict__ kv_a, bf16_t* __restrict__ kpe,
                         const float* __restrict__ cosT, const float* __restrict__ sinT) {
  int idx = blockIdx.x * blockDim.x + threadIdx.x;  // s*32 total
  int d = idx & 31, s = idx >> 5;
  const float* kp = kv_a + (size_t)s * 576 + 512;
  float c = cosT[s * 64 + d], sn = sinT[s * 64 + d];
  float x1 = kp[d], x2 = kp[d + 32];
  kpe[s * 64 + d]      = (bf16_t)(x1 * c - x2 * sn);
  kpe[s * 64 + d + 32] = (bf16_t)(x2 * c + x1 * sn);
}

// ---------------- V transpose: KV(s, h*256+128+d) -> Vt(h, d, s) ----------------
__global__ void k_v_transpose(const bf16_t* __restrict__ KV, bf16_t* __restrict__ Vt) {
  __shared__ bf16_t t[32][33];
  int h = blockIdx.x, s0 = blockIdx.y * 32, d0 = blockIdx.z * 32;
  int tx = threadIdx.x, ty = threadIdx.y;
#pragma unroll
  for (int i = 0; i < 4; ++i)
    t[ty + i * 8][tx] = KV[(size_t)(s0 + ty + i * 8) * 32768 + h * 256 + 128 + d0 + tx];
  __syncthreads();
#pragma unroll
  for (int i = 0; i < 4; ++i)
    Vt[((size_t)h * 128 + d0 + ty + i * 8) * 1024 + s0 + tx] = t[tx][ty + i * 8];
}

// ---------------- flash attention, 1 head x 16 q-rows per wave ----------------
__global__ __launch_bounds__(256) void k_attn(
    const bf16_t* __restrict__ Q, const bf16_t* __restrict__ KV,
    const bf16_t* __restrict__ KPE, const bf16_t* __restrict__ Vt,
    bf16_t* __restrict__ O) {
  const int h = blockIdx.x;
  const int qb = blockIdx.y;
  const int lane = threadIdx.x & 63, w = threadIdx.x >> 6;
  const int q0 = qb * 64 + w * 16;
  const int lr = lane & 15, lg = lane >> 4;
  __shared__ __align__(16) bf16_t pl[4][16][32];

  bf16x8 qf[6];
  {
    const bf16_t* qrow = Q + (size_t)(q0 + lr) * 24576 + h * 192;
#pragma unroll
    for (int kk = 0; kk < 6; ++kk) qf[kk] = *(const bf16x8*)&qrow[kk * 32 + lg * 8];
  }
  float m[4], l[4];
  f32x4 o[8];
#pragma unroll
  for (int r = 0; r < 4; ++r) { m[r] = -1e30f; l[r] = 0.f; }
#pragma unroll
  for (int nt = 0; nt < 8; ++nt) o[nt] = (f32x4){0.f, 0.f, 0.f, 0.f};

  const float sc = 0.07216878364870323f;  // 1/sqrt(192)
  const int kv_end = q0 + 16;
  for (int kv0 = 0; kv0 < kv_end; kv0 += 32) {
    f32x4 s0 = (f32x4){0.f, 0.f, 0.f, 0.f}, s1 = (f32x4){0.f, 0.f, 0.f, 0.f};
    const bf16_t* k0p = KV + (size_t)(kv0 + lr) * 32768 + h * 256;
    const bf16_t* k1p = KV + (size_t)(kv0 + 16 + lr) * 32768 + h * 256;
#pragma unroll
    for (int kk = 0; kk < 4; ++kk) {
      bf16x8 b0 = *(const bf16x8*)&k0p[kk * 32 + lg * 8];
      bf16x8 b1 = *(const bf16x8*)&k1p[kk * 32 + lg * 8];
      s0 = MFMA16(qf[kk], b0, s0);
      s1 = MFMA16(qf[kk], b1, s1);
    }
    const bf16_t* p0p = KPE + (size_t)(kv0 + lr) * 64;
    const bf16_t* p1p = KPE + (size_t)(kv0 + 16 + lr) * 64;
#pragma unroll
    for (int kk = 0; kk < 2; ++kk) {
      bf16x8 b0 = *(const bf16x8*)&p0p[kk * 32 + lg * 8];
      bf16x8 b1 = *(const bf16x8*)&p1p[kk * 32 + lg * 8];
      s0 = MFMA16(qf[4 + kk], b0, s0);
      s1 = MFMA16(qf[4 + kk], b1, s1);
    }
    // masked online softmax (rows owned: q0 + lg*4 + r)
    float p0[4], p1[4], pm[4];
#pragma unroll
    for (int r = 0; r < 4; ++r) {
      int qrow = q0 + lg * 4 + r;
      float v0 = s0[r] * sc, v1 = s1[r] * sc;
      if (kv0 + lr > qrow) v0 = -1e30f;
      if (kv0 + 16 + lr > qrow) v1 = -1e30f;
      p0[r] = v0; p1[r] = v1;
      pm[r] = fmaxf(v0, v1);
    }
#pragma unroll
    for (int off = 8; off > 0; off >>= 1)
#pragma unroll
      for (int r = 0; r < 4; ++r) pm[r] = fmaxf(pm[r], __shfl_xor(pm[r], off));
    float fr[4], ps[4];
#pragma unroll
    for (int r = 0; r < 4; ++r) {
      float mn = fmaxf(m[r], pm[r]);
      fr[r] = __expf(m[r] - mn);
      m[r] = mn;
      p0[r] = __expf(p0[r] - mn);
      p1[r] = __expf(p1[r] - mn);
      ps[r] = p0[r] + p1[r];
    }
#pragma unroll
    for (int off = 8; off > 0; off >>= 1)
#pragma unroll
      for (int r = 0; r < 4; ++r) ps[r] += __shfl_xor(ps[r], off);
#pragma unroll
    for (int r = 0; r < 4; ++r) l[r] = l[r] * fr[r] + ps[r];
#pragma unroll
    for (int nt = 0; nt < 8; ++nt)
#pragma unroll
      for (int r = 0; r < 4; ++r) o[nt][r] *= fr[r];
    // P -> per-wave LDS bounce to A-fragment layout
#pragma unroll
    for (int r = 0; r < 4; ++r) {
      pl[w][lg * 4 + r][lr] = (bf16_t)p0[r];
      pl[w][lg * 4 + r][16 + lr] = (bf16_t)p1[r];
    }
    bf16x8 pa = *(const bf16x8*)&pl[w][lr][lg * 8];
    const bf16_t* vb = Vt + ((size_t)h * 128) * 1024 + kv0 + lg * 8;
#pragma unroll
    for (int nt = 0; nt < 8; ++nt) {
      bf16x8 bv = *(const bf16x8*)&vb[(size_t)(nt * 16 + lr) * 1024];
      o[nt] = MFMA16(pa, bv, o[nt]);
    }
  }
#pragma unroll
  for (int nt = 0; nt < 8; ++nt)
#pragma unroll
    for (int r = 0; r < 4; ++r) {
      int row = q0 + lg * 4 + r;
      O[(size_t)row * 16384 + h * 128 + nt * 16 + lr] = (bf16_t)(o[nt][r] / l[r]);
    }
}

// =====================================================================
extern "C" void kernel_launch(void* const* d_in, const int* in_sizes, int n_in,
                              void* d_out, int out_size, void* d_ws, size_t ws_size,
                              hipStream_t stream) {
  const float* hs        = (const float*)d_in[0];
  const int*   pos       = (const int*)d_in[1];   // int64 in reference -> int32 from harness
  const float* Wqa       = (const float*)d_in[2];
  const float* wqln      = (const float*)d_in[3];
  const float* Wqb       = (const float*)d_in[4];
  const float* Wkva      = (const float*)d_in[5];
  const float* wkln      = (const float*)d_in[6];
  const float* Wkvb      = (const float*)d_in[7];
  const float* Wo        = (const float*)d_in[8];
  float* out = (float*)d_out;
  (void)in_sizes; (void)n_in; (void)out_size; (void)ws_size;

  char* p = (char*)d_ws;
  size_t off = 0;
  auto alloc = [&](size_t bytes) { void* r = p + off; off += (bytes + 255) & ~(size_t)255; return r; };

  // ---- persistent region (live until end) ----
  bf16_t* Qb   = (bf16_t*)alloc((size_t)1024 * 24576 * 2);  // q after q_b proj (+rope)
  bf16_t* KVb  = (bf16_t*)alloc((size_t)1024 * 32768 * 2);  // kv_b output: (s, h*256 + [k_nope|v])
  bf16_t* Vt   = (bf16_t*)alloc((size_t)128 * 128 * 1024 * 2);  // V transposed (h, d, s)
  bf16_t* Ob   = (bf16_t*)alloc((size_t)1024 * 16384 * 2);  // attention out (s, h*128+d)
  bf16_t* ckv  = (bf16_t*)alloc((size_t)1024 * 512 * 2);
  bf16_t* kpe  = (bf16_t*)alloc((size_t)1024 * 64 * 2);
  float*  cosT = (float*)alloc((size_t)1024 * 64 * 4);
  float*  sinT = (float*)alloc((size_t)1024 * 64 * 4);

  // ---- scratch region (dead before GEMM5); WoT aliases it ----
  size_t scratch0 = off;
  bf16_t* xb    = (bf16_t*)alloc((size_t)1024 * 7168 * 2);
  bf16_t* WqaT  = (bf16_t*)alloc((size_t)1536 * 7168 * 2);
  bf16_t* WqbT  = (bf16_t*)alloc((size_t)24576 * 1536 * 2);
  bf16_t* WkvaT = (bf16_t*)alloc((size_t)640 * 7168 * 2);   // padded 576->640, pad zeroed
  bf16_t* WkvbT = (bf16_t*)alloc((size_t)32768 * 512 * 2);
  float*  qa    = (float*)alloc((size_t)1024 * 1536 * 4);
  bf16_t* qc    = (bf16_t*)alloc((size_t)1024 * 1536 * 2);
  float*  kva   = (float*)alloc((size_t)1024 * 576 * 4);
  bf16_t* WoT   = (bf16_t*)(p + scratch0);                  // 7168x16384 bf16, aliases scratch

  // ---- stage 0: conversions / tables ----
  k_f32_to_bf16<<<2048, 256, 0, stream>>>(hs, xb, (size_t)1024 * 7168 / 4);
  k_transpose_f32_bf16<<<dim3(7168 / 32, 1536 / 32), dim3(32, 8), 0, stream>>>(Wqa, WqaT, 7168, 1536, 1536, 7168);
  k_transpose_f32_bf16<<<dim3(1536 / 32, 24576 / 32), dim3(32, 8), 0, stream>>>(Wqb, WqbT, 1536, 24576, 24576, 1536);
  k_transpose_f32_bf16<<<dim3(7168 / 32, 640 / 32), dim3(32, 8), 0, stream>>>(Wkva, WkvaT, 7168, 576, 576, 7168);
  k_transpose_f32_bf16<<<dim3(512 / 32, 32768 / 32), dim3(32, 8), 0, stream>>>(Wkvb, WkvbT, 512, 32768, 32768, 512);
  k_build_rope<<<1024, 64, 0, stream>>>(pos, cosT, sinT);

  // ---- q path ----
  k_gemm_tn<64, 128, 2, 2, 1><<<dim3(1536 / 128, 1024 / 64), 256, 0, stream>>>(
      xb, WqaT, qa, nullptr, 1536, 7168, 7168, 7168, 1536);
  k_rmsnorm<1536><<<1024, 256, 0, stream>>>(qa, wqln, qc, 1536, 1536);
  k_gemm_tn<128, 128, 2, 2, 0><<<dim3(24576 / 128, 1024 / 128), 256, 0, stream>>>(
      qc, WqbT, nullptr, Qb, 24576, 1536, 1536, 1536, 24576);
  k_rope_q<<<(1024 * 128 * 32) / 256, 256, 0, stream>>>(Qb, cosT, sinT);

  // ---- kv path ----
  k_gemm_tn<64, 64, 2, 2, 1><<<dim3(640 / 64, 1024 / 64), 256, 0, stream>>>(
      xb, WkvaT, kva, nullptr, 576, 7168, 7168, 7168, 576);
  k_rmsnorm<512><<<1024, 256, 0, stream>>>(kva, wkln, ckv, 576, 512);
  k_rope_k<<<(1024 * 32) / 256, 256, 0, stream>>>(kva, kpe, cosT, sinT);
  k_gemm_tn<128, 128, 2, 2, 0><<<dim3(32768 / 128, 1024 / 128), 256, 0, stream>>>(
      ckv, WkvbT, nullptr, KVb, 32768, 512, 512, 512, 32768);
  k_v_transpose<<<dim3(128, 32, 4), dim3(32, 8), 0, stream>>>(KVb, Vt);

  // ---- Wo transpose now (scratch region is dead -> WoT alias is safe) ----
  k_transpose_f32_bf16<<<dim3(16384 / 32, 7168 / 32), dim3(32, 8), 0, stream>>>(Wo, WoT, 16384, 7168, 7168, 16384);

  // ---- attention ----
  k_attn<<<dim3(128, 16), 256, 0, stream>>>(Qb, KVb, kpe, Vt, Ob);

  // ---- output projection ----
  k_gemm_tn<128, 128, 2, 2, 1><<<dim3(7168 / 128, 1024 / 128), 256, 0, stream>>>(
      Ob, WoT, out, nullptr, 7168, 16384, 16384, 16384, 7168);
}